// Round 12
// baseline (331.567 us; speedup 1.0000x reference)
//
#include <hip/hip_runtime.h>
#include <hip/hip_bf16.h>
#include <hip/hip_fp16.h>

#define NNODES 50000
#define MPAD   50048
#define NEDGES 800000
#define ETOT   (NEDGES + NNODES)
#define FIN    256
#define HEADS  4
#define C1     32
#define D1     128
#define C2     40
#define D2     160

#define CB   ((ETOT + 255) / 256)    // 3321 edge-parallel blocks
#define RB1  144                      // repack1 blocks
#define RB2  88                       // repack2 blocks
#define ZB   49                       // zero-counts blocks (12500 uint4 threads)
#define GB1  (MPAD / 64)              // 782 gemm1 blocks
#define GB1A 391                      // gemm1 half A (in count kernel)
#define GB1B (GB1 - GB1A)             // gemm1 half B (in scan kernel)

typedef unsigned short u16;
typedef short v8s __attribute__((ext_vector_type(8)));
typedef float v4f __attribute__((ext_vector_type(4)));

__device__ __forceinline__ float bf2f(unsigned u) {
    union { unsigned u; float f; } x; x.u = u << 16; return x.f;
}
__device__ __forceinline__ u16 f2bf(float f) {        // RNE
    unsigned u = __float_as_uint(f);
    return (u16)((u + 0x7fff + ((u >> 16) & 1)) >> 16);
}
__device__ __forceinline__ unsigned pk_bf16(float a, float b) {
    unsigned ua = (__float_as_uint(a) + 0x8000u) >> 16;
    unsigned ub = (__float_as_uint(b) + 0x8000u) & 0xffff0000u;
    return ub | ua;
}
__device__ __forceinline__ float wave_sum(float v) {
    #pragma unroll
    for (int m = 32; m > 0; m >>= 1) v += __shfl_xor(v, m, 64);
    return v;
}
__device__ __forceinline__ void wave_sum2(float& a, float& b) {
    #pragma unroll
    for (int m = 32; m > 0; m >>= 1) {
        a += __shfl_xor(a, m, 64);
        b += __shfl_xor(b, m, 64);
    }
}
__device__ __forceinline__ float leaky(float x) { return fmaxf(x, 0.2f * x); }

// ---------------- repack W[K,N] f32 -> MFMA B-fragment order bf16, plus ext
// 16-col tile: col h = W @ a_src_h, col 4+h = W @ a_dst_h
__device__ __forceinline__ void repack_body(const float* __restrict__ W,
                                            const float* __restrict__ as,
                                            const float* __restrict__ ad,
                                            u16* __restrict__ Wf,
                                            int K, int N, int C, int total, int idx) {
    if (idx >= total) return;
    int KS = K >> 5, NT = N >> 4;
    int j = idx & 7, lane = (idx >> 3) & 63;
    int rest = idx >> 9;
    int ks = rest % KS, nt = rest / KS;
    int k = ks * 32 + (lane >> 4) * 8 + j;
    int n16 = lane & 15;
    float val = 0.f;
    if (nt < NT) {
        val = W[(size_t)k * N + nt * 16 + n16];
    } else if (n16 < 8) {
        int h = n16 & 3;
        const float* av = (n16 < 4) ? as : ad;
        float s = 0.f;
        for (int c = 0; c < C; c++) s += W[(size_t)k * N + h * C + c] * av[h * C + c];
        val = s;
    }
    Wf[idx] = f2bf(val);
}

// ---------------- MFMA GEMM body + fused attention dots
template <bool AF32, int KK, int NT>
__device__ __forceinline__ void gemm_body(const void* __restrict__ Aptr,
                                          const u16* __restrict__ Wf,
                                          u16* __restrict__ Out,
                                          float* __restrict__ ssrc,
                                          float* __restrict__ sdst, int M, int bid) {
    const int KS = KK / 32;
    const int NCOL = NT * 16;
    int wid = threadIdx.x >> 6, lane = threadIdx.x & 63;
    int r0 = bid * 64 + wid * 16;
    int m = lane & 15, quad = lane >> 4;
    int row = r0 + m;
    bool rowok = row < M;

    v8s a[KS];
    if (AF32) {
        const float* ap = (const float*)Aptr + (size_t)(rowok ? row : 0) * KK + quad * 8;
        #pragma unroll
        for (int ks = 0; ks < KS; ks++) {
            if (rowok) {
                float4 fa = *(const float4*)(ap + ks * 32);
                float4 fb = *(const float4*)(ap + ks * 32 + 4);
                union { unsigned u[4]; v8s v; } c;
                c.u[0] = pk_bf16(fa.x, fa.y); c.u[1] = pk_bf16(fa.z, fa.w);
                c.u[2] = pk_bf16(fb.x, fb.y); c.u[3] = pk_bf16(fb.z, fb.w);
                a[ks] = c.v;
            } else {
                a[ks] = (v8s){0,0,0,0,0,0,0,0};
            }
        }
    } else {
        const u16* ap = (const u16*)Aptr + (size_t)(rowok ? row : 0) * KK + quad * 8;
        #pragma unroll
        for (int ks = 0; ks < KS; ks++)
            a[ks] = rowok ? *(const v8s*)(ap + ks * 32) : (v8s){0,0,0,0,0,0,0,0};
    }

    const v8s* bp0 = (const v8s*)Wf + lane;
    #pragma unroll 2
    for (int nt = 0; nt < NT; nt++) {
        v4f acc = {0.f, 0.f, 0.f, 0.f};
        const v8s* bp = bp0 + nt * KS * 64;
        #pragma unroll
        for (int ks = 0; ks < KS; ks++)
            acc = __builtin_amdgcn_mfma_f32_16x16x32_bf16(a[ks], bp[ks * 64], acc, 0, 0, 0);
        int col = nt * 16 + m;
        #pragma unroll
        for (int reg = 0; reg < 4; reg++) {
            int r = r0 + quad * 4 + reg;
            if (r < M) Out[(size_t)r * NCOL + col] = f2bf(acc[reg]);
        }
    }
    {
        v4f acc = {0.f, 0.f, 0.f, 0.f};
        const v8s* bp = bp0 + NT * KS * 64;
        #pragma unroll
        for (int ks = 0; ks < KS; ks++)
            acc = __builtin_amdgcn_mfma_f32_16x16x32_bf16(a[ks], bp[ks * 64], acc, 0, 0, 0);
        if (m < 8) {
            float* tgt = (m < 4) ? ssrc : sdst;
            int h = m & 3;
            #pragma unroll
            for (int reg = 0; reg < 4; reg++) {
                int r = r0 + quad * 4 + reg;
                if (r < M) tgt[r * 4 + h] = acc[reg];
            }
        }
    }
}

// ---------------- K1: zero counts + both weight repacks
__global__ __launch_bounds__(256) void zero_repack(int* __restrict__ counts,
                                                   const float* __restrict__ W1,
                                                   const float* __restrict__ as1,
                                                   const float* __restrict__ ad1,
                                                   u16* __restrict__ Wf1,
                                                   const float* __restrict__ W2,
                                                   const float* __restrict__ as2,
                                                   const float* __restrict__ ad2,
                                                   u16* __restrict__ Wf2) {
    int b = blockIdx.x;
    if (b < ZB) {
        int i4 = (b * 256 + threadIdx.x) * 4;
        if (i4 < NNODES) *(int4*)(counts + i4) = make_int4(0, 0, 0, 0);
    } else if (b < ZB + RB1) {
        repack_body(W1, as1, ad1, Wf1, FIN, D1, C1, 9 * 8 * 512, (b - ZB) * 256 + threadIdx.x);
    } else {
        repack_body(W2, as2, ad2, Wf2, D1, D2, C2, 11 * 4 * 512, (b - ZB - RB1) * 256 + threadIdx.x);
    }
}

// ---------------- K2: count histogram + rank capture, merged with gemm1 half A
__global__ __launch_bounds__(256) void count_gemm1a(const int* __restrict__ ei,
                                                    int* __restrict__ counts,
                                                    u16* __restrict__ pos,
                                                    const float* __restrict__ x,
                                                    const u16* __restrict__ Wf1,
                                                    u16* __restrict__ BH1,
                                                    float* __restrict__ ssrc,
                                                    float* __restrict__ sdst) {
    int b = blockIdx.x;
    if (b < CB) {
        int t = b * 256 + threadIdx.x;
        if (t >= ETOT) return;
        int d = (t < NEDGES) ? ei[NEDGES + t] : (t - NEDGES);
        pos[t] = (u16)atomicAdd(&counts[d], 1);
    } else {
        gemm_body<true, FIN, 8>(x, Wf1, BH1, ssrc, sdst, NNODES, b - CB);
    }
}

// ---------------- K3: exclusive scan (block 0, 256 threads) + gemm1 half B
__global__ __launch_bounds__(256) void scan_gemm1b(const int* __restrict__ counts,
                                                   int* __restrict__ rowptr,
                                                   const float* __restrict__ x,
                                                   const u16* __restrict__ Wf1,
                                                   u16* __restrict__ BH1,
                                                   float* __restrict__ ssrc,
                                                   float* __restrict__ sdst) {
    if (blockIdx.x > 0) {
        gemm_body<true, FIN, 8>(x, Wf1, BH1, ssrc, sdst, NNODES, GB1A + blockIdx.x - 1);
        return;
    }
    __shared__ int wsum[4];
    __shared__ int srun;
    const int t = threadIdx.x;
    const int lane = t & 63, wid = t >> 6;
    if (t == 0) srun = 0;
    __syncthreads();
    for (int base = 0; base < NNODES; base += 1024) {
        int i4 = base + t * 4;
        int4 v = make_int4(0, 0, 0, 0);
        if (i4 < NNODES) v = *(const int4*)(counts + i4);
        int tsum = v.x + v.y + v.z + v.w;
        int xp = tsum;
        #pragma unroll
        for (int off = 1; off < 64; off <<= 1) {
            int y = __shfl_up(xp, off, 64);
            if (lane >= off) xp += y;
        }
        if (lane == 63) wsum[wid] = xp;
        __syncthreads();
        if (wid == 0) {
            int w = (lane < 4) ? wsum[lane] : 0;
            #pragma unroll
            for (int off = 1; off < 4; off <<= 1) {
                int y = __shfl_up(w, off, 64);
                if (lane >= off) w += y;
            }
            if (lane < 4) wsum[lane] = w;
        }
        __syncthreads();
        int wbase = (wid > 0) ? wsum[wid - 1] : 0;
        int run = srun;
        int pre = run + wbase + xp - tsum;
        if (i4 < NNODES) {
            rowptr[i4]     = pre;
            rowptr[i4 + 1] = pre + v.x;
            rowptr[i4 + 2] = pre + v.x + v.y;
            rowptr[i4 + 3] = pre + v.x + v.y + v.z;
        }
        __syncthreads();
        if (t == 255) srun = run + wsum[3];
        __syncthreads();
    }
    if (t == 0) rowptr[NNODES] = srun;
}

// ---------------- K4: CSR fill — no atomics, non-temporal scattered store
__global__ __launch_bounds__(256) void fill_k(const int* __restrict__ ei,
                                              const int* __restrict__ rowptr,
                                              const u16* __restrict__ pos,
                                              u16* __restrict__ esrc) {
    int t = blockIdx.x * blockDim.x + threadIdx.x;
    if (t >= ETOT) return;
    int s, d;
    if (t < NEDGES) { s = ei[t]; d = ei[NEDGES + t]; } else { s = t - NEDGES; d = s; }
    int idx = rowptr[d] + (int)pos[t];
    __builtin_nontemporal_store((u16)s, &esrc[idx]);
}

template <int KK, int NT>
__global__ __launch_bounds__(256) void gemm_mfma(const u16* __restrict__ A,
                                                 const u16* __restrict__ Wf,
                                                 u16* __restrict__ Out,
                                                 float* __restrict__ ssrc,
                                                 float* __restrict__ sdst, int M) {
    gemm_body<false, KK, NT>(A, Wf, Out, ssrc, sdst, M, blockIdx.x);
}

// phase A: 32-edge tile, head-parallel; lane = hh*16 + jj handles edges jj, jj+16.
// max-free softmax (e bounded; shift-invariance). den per head via 4-step subgroup shuffle.
#define PHASE_A32(SRC_ARR, P_ARR)                                                  \
    int nj = end - tb; if (nj > 32) nj = 32;                                       \
    bool on1 = jj < nj, on2 = jj + 16 < nj;                                        \
    int sE1 = on1 ? (int)esrc[tb + jj] : 0;                                        \
    int sE2 = on2 ? (int)esrc[tb + 16 + jj] : 0;                                   \
    if (hh == 0) { if (on1) SRC_ARR[wid][jj] = sE1;                                \
                   if (on2) SRC_ARR[wid][16 + jj] = sE2; }                         \
    float pa = on1 ? __expf(leaky(ssrc[sE1 * 4 + hh] + sdh)) : 0.f;                \
    float pb = on2 ? __expf(leaky(ssrc[sE2 * 4 + hh] + sdh)) : 0.f;                \
    float tsum = pa + pb;                                                          \
    tsum += __shfl_xor(tsum, 1, 64); tsum += __shfl_xor(tsum, 2, 64);              \
    tsum += __shfl_xor(tsum, 4, 64); tsum += __shfl_xor(tsum, 8, 64);              \
    den += tsum;                                                                   \
    if (on1) P_ARR[wid][hh][jj] = pa;                                              \
    if (on2) P_ARR[wid][hh][16 + jj] = pb;

// ---------------- layer 1: gather + softmax + bias + ELU + LN -> bf16 BOb
__global__ __launch_bounds__(256) void gat_fused1(const int* __restrict__ rowptr,
                                                  const u16* __restrict__ esrc,
                                                  const float* __restrict__ ssrc,
                                                  const float* __restrict__ sdst,
                                                  const u16* __restrict__ BH,
                                                  const float* __restrict__ b1,
                                                  const float* __restrict__ g,
                                                  const float* __restrict__ be,
                                                  u16* __restrict__ BOb) {
    __shared__ int   s_src[4][32];
    __shared__ float s_p[4][4][32];
    __shared__ float s_den[4][4];
    int wid = threadIdx.x >> 6, lane = threadIdx.x & 63;
    int node = blockIdx.x * 4 + wid;
    int jj = lane & 15, hh = lane >> 4;
    int l8 = lane & 15, grp = lane >> 4;
    int head = l8 >> 2;
    float sdh = sdst[node * 4 + hh];
    int beg = rowptr[node], end = rowptr[node + 1];
    float den = 0.f;
    float acc[8];
    #pragma unroll
    for (int i = 0; i < 8; i++) acc[i] = 0.f;

    for (int tb = beg; tb < end; tb += 32) {
        PHASE_A32(s_src, s_p)
        #pragma unroll 8
        for (int j = grp; j < nj; j += 4) {
            int sj = s_src[wid][j];
            float al = s_p[wid][head][j];
            uint4 h = *(const uint4*)(BH + (size_t)sj * D1 + l8 * 8);
            acc[0] += al * bf2f(h.x & 0xffffu); acc[1] += al * bf2f(h.x >> 16);
            acc[2] += al * bf2f(h.y & 0xffffu); acc[3] += al * bf2f(h.y >> 16);
            acc[4] += al * bf2f(h.z & 0xffffu); acc[5] += al * bf2f(h.z >> 16);
            acc[6] += al * bf2f(h.w & 0xffffu); acc[7] += al * bf2f(h.w >> 16);
        }
    }
    if (jj == 0) s_den[wid][hh] = den;
    #pragma unroll
    for (int i = 0; i < 8; i++) {
        acc[i] += __shfl_xor(acc[i], 16, 64);
        acc[i] += __shfl_xor(acc[i], 32, 64);
    }
    float rden = 1.f / s_den[wid][head];
    float4 bA = *(const float4*)(b1 + l8 * 8), bB = *(const float4*)(b1 + l8 * 8 + 4);
    float v[8];
    v[0] = acc[0] * rden + bA.x; v[1] = acc[1] * rden + bA.y;
    v[2] = acc[2] * rden + bA.z; v[3] = acc[3] * rden + bA.w;
    v[4] = acc[4] * rden + bB.x; v[5] = acc[5] * rden + bB.y;
    v[6] = acc[6] * rden + bB.z; v[7] = acc[7] * rden + bB.w;
    float s8 = 0.f, q8 = 0.f;
    #pragma unroll
    for (int i = 0; i < 8; i++) {
        v[i] = v[i] > 0.f ? v[i] : __expf(v[i]) - 1.f;
        s8 += v[i]; q8 += v[i] * v[i];
    }
    wave_sum2(s8, q8);                              // chans counted 4x -> /512
    float mu = s8 * (1.f / 512.f);
    float var = q8 * (1.f / 512.f) - mu * mu;
    float rs = rsqrtf(var + 1e-5f);
    if (grp == 0) {
        float4 gA = *(const float4*)(g + l8 * 8),  gB = *(const float4*)(g + l8 * 8 + 4);
        float4 eA = *(const float4*)(be + l8 * 8), eB = *(const float4*)(be + l8 * 8 + 4);
        u16 o[8] = {f2bf((v[0] - mu) * rs * gA.x + eA.x), f2bf((v[1] - mu) * rs * gA.y + eA.y),
                    f2bf((v[2] - mu) * rs * gA.z + eA.z), f2bf((v[3] - mu) * rs * gA.w + eA.w),
                    f2bf((v[4] - mu) * rs * gB.x + eB.x), f2bf((v[5] - mu) * rs * gB.y + eB.y),
                    f2bf((v[6] - mu) * rs * gB.z + eB.z), f2bf((v[7] - mu) * rs * gB.w + eB.w)};
        *(uint4*)(BOb + (size_t)node * D1 + l8 * 8) = *(uint4*)o;
    }
}

// ---------------- layer 2: gather + softmax + head-mean + LN + log_softmax -> f32 out
__global__ __launch_bounds__(256) void gat_fused2(const int* __restrict__ rowptr,
                                                  const u16* __restrict__ esrc,
                                                  const float* __restrict__ ssrc,
                                                  const float* __restrict__ sdst,
                                                  const u16* __restrict__ BH,
                                                  const float* __restrict__ b2,
                                                  const float* __restrict__ g,
                                                  const float* __restrict__ be,
                                                  float* __restrict__ out) {
    __shared__ int   s_src[4][32];
    __shared__ float s_p[4][4][32];
    __shared__ float s_den[4][4];
    __shared__ float scr3[4][3][160];
    int wid = threadIdx.x >> 6, lane = threadIdx.x & 63;
    int node = blockIdx.x * 4 + wid;
    int jj = lane & 15, hh = lane >> 4;
    int grp = lane / 20;                    // 3 => idle in phase B
    int glane = lane - grp * 20;
    int head = glane / 5;
    float sdh = sdst[node * 4 + hh];
    int beg = rowptr[node], end = rowptr[node + 1];
    float den = 0.f;
    float acc[8];
    #pragma unroll
    for (int i = 0; i < 8; i++) acc[i] = 0.f;

    for (int tb = beg; tb < end; tb += 32) {
        PHASE_A32(s_src, s_p)
        if (grp < 3) {
            #pragma unroll 4
            for (int j = grp; j < nj; j += 3) {
                int sj = s_src[wid][j];
                float al = s_p[wid][head][j];
                uint4 h = *(const uint4*)(BH + (size_t)sj * D2 + glane * 8);
                acc[0] += al * bf2f(h.x & 0xffffu); acc[1] += al * bf2f(h.x >> 16);
                acc[2] += al * bf2f(h.y & 0xffffu); acc[3] += al * bf2f(h.y >> 16);
                acc[4] += al * bf2f(h.z & 0xffffu); acc[5] += al * bf2f(h.z >> 16);
                acc[6] += al * bf2f(h.w & 0xffffu); acc[7] += al * bf2f(h.w >> 16);
            }
        }
    }
    if (jj == 0) s_den[wid][hh] = den;
    if (grp < 3) {
        float rden = 1.f / s_den[wid][head];
        float4 oA = {acc[0] * rden, acc[1] * rden, acc[2] * rden, acc[3] * rden};
        float4 oB = {acc[4] * rden, acc[5] * rden, acc[6] * rden, acc[7] * rden};
        *(float4*)&scr3[wid][grp][glane * 8]     = oA;
        *(float4*)&scr3[wid][grp][glane * 8 + 4] = oB;
    }
    bool act = lane < 40;
    int c = act ? lane : 0;
    float o = 0.f;
    if (act) {
        float s = 0.f;
        #pragma unroll
        for (int k = 0; k < 4; k++)
            #pragma unroll
            for (int gg = 0; gg < 3; gg++) s += scr3[wid][gg][c + 40 * k];
        o = 0.25f * s + b2[c];
    }
    float so = act ? o : 0.f, qo = so * o;
    wave_sum2(so, qo);
    float mu = so * (1.f / 40.f);
    float var = qo * (1.f / 40.f) - mu * mu;
    float rs = rsqrtf(var + 1e-5f);
    // y bounded by sqrt(40)*|g|+|be| -> exp safe without max-subtraction
    float y = act ? (o - mu) * rs * g[c] + be[c] : 0.f;
    float ex = act ? __expf(y) : 0.f;
    float lse = __logf(wave_sum(ex));
    if (act) out[(size_t)node * 40 + c] = y - lse;
}

extern "C" void kernel_launch(void* const* d_in, const int* in_sizes, int n_in,
                              void* d_out, int out_size, void* d_ws, size_t ws_size,
                              hipStream_t stream) {
    const float* x   = (const float*)d_in[0];
    const int*   ei  = (const int*)d_in[1];
    const float* W1  = (const float*)d_in[2];
    const float* as1 = (const float*)d_in[3];
    const float* ad1 = (const float*)d_in[4];
    const float* b1  = (const float*)d_in[5];
    const float* W2  = (const float*)d_in[6];
    const float* as2 = (const float*)d_in[7];
    const float* ad2 = (const float*)d_in[8];
    const float* b2  = (const float*)d_in[9];
    const float* g0  = (const float*)d_in[10];
    const float* be0 = (const float*)d_in[11];
    const float* g1  = (const float*)d_in[12];
    const float* be1 = (const float*)d_in[13];

    float* ws = (float*)d_ws;
    u16*   BH1    = (u16*)ws;                       // 50000*128 bf16 = 3,200,000 f
    u16*   BH2    = (u16*)(ws + 3200000);           // 50000*160 bf16 = 4,000,000 f
    u16*   BOb    = (u16*)(ws + 7200000);           // 50000*128 bf16 = 3,200,000 f
    float* ssrc   = ws + 10400000;                  // 200,000 f
    float* sdst   = ws + 10600000;                  // 200,000 f
    int*   rowptr = (int*)(ws + 10800000);          // 50,001 (+3 pad)
    u16*   esrc   = (u16*)(ws + 10850004);          // ETOT u16 = 425,000 f
    int*   counts = (int*)(ws + 11275004);          // 50,000
    u16*   pos    = (u16*)(ws + 11325004);          // ETOT u16 = 425,000 f
    u16*   Wf1    = (u16*)(ws + 11750004);          // 36,864 bf16
    u16*   Wf2    = (u16*)(ws + 11768436);          // 22,528 bf16
    // end: 11,779,700 f = 47.1 MB

    const int nb4 = NNODES / 4;

    // K1: zero counts + weight repacks
    zero_repack<<<ZB + RB1 + RB2, 256, 0, stream>>>(counts, W1, as1, ad1, Wf1,
                                                    W2, as2, ad2, Wf2);
    // K2: histogram + rank capture, overlapped with gemm1 half A
    count_gemm1a<<<CB + GB1A, 256, 0, stream>>>(ei, counts, pos, x, Wf1, BH1, ssrc, sdst);
    // K3: scan (block 0) + gemm1 half B
    scan_gemm1b<<<1 + GB1B, 256, 0, stream>>>(counts, rowptr, x, Wf1, BH1, ssrc, sdst);
    // K4: atomic-free CSR fill (non-temporal scattered stores)
    fill_k<<<CB, 256, 0, stream>>>(ei, rowptr, pos, esrc);
    // layer 1 aggregate
    gat_fused1<<<nb4, 256, 0, stream>>>(rowptr, esrc, ssrc, sdst, BH1, b1, g0, be0, BOb);
    // layer 2
    gemm_mfma<D1, 10><<<GB1, 256, 0, stream>>>(BOb, Wf2, BH2, ssrc, sdst, NNODES);
    gat_fused2<<<nb4, 256, 0, stream>>>(rowptr, esrc, ssrc, sdst, BH2, b2, g1, be1, (float*)d_out);
}